// Round 19
// baseline (130.978 us; speedup 1.0000x reference)
//
#include <hip/hip_runtime.h>
#include <hip/hip_bf16.h>
#include <stdint.h>

typedef short bf16x8 __attribute__((ext_vector_type(8)));
typedef float f32x4 __attribute__((ext_vector_type(4)));

#define D  512
#define NB 4096
#define NT 8192

__device__ __forceinline__ unsigned short f2bf(float f) {
    __hip_bfloat16 h = __float2bfloat16(f);
    return *reinterpret_cast<unsigned short*>(&h);
}

// Fused fp32->bf16 convert + row squared-norm for BOTH inputs; x rows also
// write the fp32 passthrough (output 0). One wave per row. HBM-floor bound.
__global__ __launch_bounds__(256) void prep_kernel(
    const float* __restrict__ x, const float* __restrict__ y,
    unsigned short* __restrict__ xb, unsigned short* __restrict__ yb,
    float* __restrict__ x2, float* __restrict__ y2, float* __restrict__ copy)
{
    const int grow = blockIdx.x * 4 + (threadIdx.x >> 6);
    const int lane = threadIdx.x & 63;
    const bool isX = grow < NB;
    const int row  = isX ? grow : grow - NB;
    const float* src = isX ? x : y;
    unsigned short* dst = isX ? xb : yb;
    float* norms = isX ? x2 : y2;

    const float4* rp = reinterpret_cast<const float4*>(src + (size_t)row * D);
    float4 v0 = rp[lane * 2];
    float4 v1 = rp[lane * 2 + 1];
    if (isX) {
        float4* cp = reinterpret_cast<float4*>(copy + (size_t)row * D);
        cp[lane * 2]     = v0;
        cp[lane * 2 + 1] = v1;
    }
    float s = v0.x*v0.x + v0.y*v0.y + v0.z*v0.z + v0.w*v0.w
            + v1.x*v1.x + v1.y*v1.y + v1.z*v1.z + v1.w*v1.w;
    union { unsigned short h[8]; int4 v; } u;
    u.h[0] = f2bf(v0.x); u.h[1] = f2bf(v0.y); u.h[2] = f2bf(v0.z); u.h[3] = f2bf(v0.w);
    u.h[4] = f2bf(v1.x); u.h[5] = f2bf(v1.y); u.h[6] = f2bf(v1.z); u.h[7] = f2bf(v1.w);
    reinterpret_cast<int4*>(dst + (size_t)row * D)[lane] = u.v;
    #pragma unroll
    for (int off = 32; off > 0; off >>= 1) s += __shfl_xor(s, off);
    if (lane == 0) norms[row] = s;
}

// R17 (m97-faithful: 128x128 tile, BK=64, 4 waves 2x2, single 32 KiB LDS
// buffer, drain-per-K-step; 57.95 µs) with ONE change: occupancy 4 -> 5
// blocks/CU. LDS 5x32 KiB = 160 KiB = full CU capacity; VGPR must fit
// 512/5 = 102, so the MFMA cluster is split to halve b-frag liveness
// (read b[0..1] -> 8 MFMA n=0,1 -> read b[2..3] -> 8 MFMA n=2,3; peak
// live ~= acc 64 + a 16 + b 8 + addr ~12 ~= 100). Accumulation order per
// acc[m][n] unchanged. Occupancy is the only lever that has gained all
// session (R16 +1.6, R17 +1.1); this is its last rung.
__global__ __launch_bounds__(256, 5) void gemm_sim_kernel(
    const unsigned short* __restrict__ X, const unsigned short* __restrict__ Y,
    const float* __restrict__ x2, const float* __restrict__ y2,
    float* __restrict__ out)
{
    __shared__ alignas(16) unsigned short lds[16384];   // 32 KiB

    const int t    = threadIdx.x;
    const int lane = t & 63;
    const int w    = t >> 6;          // 0..3
    const int wr   = w >> 1;          // 0..1 (row half, 64 rows)
    const int wc   = w & 1;           // 0..1 (col half, 64 cols)

    // 2048 blocks; per XCD 16 rowTiles x 16 colTiles (A 2MB + B 2MB L2-fit).
    const int bid = blockIdx.x;
    const int xcd = bid & 7;
    const int idx = bid >> 3;                          // 0..255
    const int rowBase = ((xcd & 1) * 16 + (idx & 15)) * 128;
    const int colBase = ((xcd >> 1) * 16 + (idx >> 4)) * 128;

    // Staging: thread t writes 16 B (8 ushorts) at LDS off t*8 (+L*2048),
    // i.e. row (t>>3)+L*32, stored chunk t&7. Source pre-swizzle (rule #21):
    // global chunk g = (t&7) ^ ((t>>3)&7)  (row&7 invariant under +32).
    const int g = ((t & 7) ^ ((t >> 3) & 7)) * 8;
    const unsigned short* gA = X + (size_t)(rowBase + (t >> 3)) * D + g;
    const unsigned short* gB = Y + (size_t)(colBase + (t >> 3)) * D + g;

    // Read-side swizzled chunk (per kk half): sc = (kk*4 + (lane>>4)) ^ (lane&7).
    int sc[2];
    #pragma unroll
    for (int kk = 0; kk < 2; ++kk)
        sc[kk] = (((kk << 2) | (lane >> 4)) ^ (lane & 7)) * 8;
    const int arow = (wr * 64 + (lane & 15)) * 64;          // + m*16*64 + sc
    const int brow = 8192 + (wc * 64 + (lane & 15)) * 64;   // + n*16*64 + sc

    f32x4 acc[4][4] = {};

#define STAGE(KT) do { \
    _Pragma("unroll") \
    for (int L = 0; L < 4; ++L) { \
        __builtin_amdgcn_global_load_lds( \
            (const __attribute__((address_space(1))) void*)(gA + (size_t)L * 32 * D + (KT) * 64), \
            (__attribute__((address_space(3))) void*)(lds + t * 8 + L * 2048), 16, 0, 0); \
        __builtin_amdgcn_global_load_lds( \
            (const __attribute__((address_space(1))) void*)(gB + (size_t)L * 32 * D + (KT) * 64), \
            (__attribute__((address_space(3))) void*)(lds + 8192 + t * 8 + L * 2048), 16, 0, 0); \
    } \
} while (0)

    // 8 K-steps (K=512 / BK=64), single-buffer drain schedule.
#pragma unroll
    for (int kt = 0; kt < 8; ++kt) {
        STAGE(kt);
        asm volatile("s_waitcnt vmcnt(0)" ::: "memory");
        __builtin_amdgcn_s_barrier();
        #pragma unroll
        for (int kk = 0; kk < 2; ++kk) {
            bf16x8 a[4];
            #pragma unroll
            for (int m = 0; m < 4; ++m)
                a[m] = *(const bf16x8*)(lds + arow + m * 1024 + sc[kk]);
            // Half 1: b0,b1 live only here.
            {
                bf16x8 b0 = *(const bf16x8*)(lds + brow + 0 * 1024 + sc[kk]);
                bf16x8 b1 = *(const bf16x8*)(lds + brow + 1 * 1024 + sc[kk]);
                __builtin_amdgcn_s_setprio(1);
                #pragma unroll
                for (int m = 0; m < 4; ++m) {
                    acc[m][0] = __builtin_amdgcn_mfma_f32_16x16x32_bf16(a[m], b0, acc[m][0], 0, 0, 0);
                    acc[m][1] = __builtin_amdgcn_mfma_f32_16x16x32_bf16(a[m], b1, acc[m][1], 0, 0, 0);
                }
                __builtin_amdgcn_s_setprio(0);
            }
            // Half 2: b2,b3.
            {
                bf16x8 b2 = *(const bf16x8*)(lds + brow + 2 * 1024 + sc[kk]);
                bf16x8 b3 = *(const bf16x8*)(lds + brow + 3 * 1024 + sc[kk]);
                __builtin_amdgcn_s_setprio(1);
                #pragma unroll
                for (int m = 0; m < 4; ++m) {
                    acc[m][2] = __builtin_amdgcn_mfma_f32_16x16x32_bf16(a[m], b2, acc[m][2], 0, 0, 0);
                    acc[m][3] = __builtin_amdgcn_mfma_f32_16x16x32_bf16(a[m], b3, acc[m][3], 0, 0, 0);
                }
                __builtin_amdgcn_s_setprio(0);
            }
        }
        asm volatile("s_waitcnt lgkmcnt(0)" ::: "memory");
        if (kt < 7) __builtin_amdgcn_s_barrier();
    }
#undef STAGE

    // Epilogue: C/D layout col = lane&15, row = (lane>>4)*4 + reg.
    const int col0 = colBase + wc * 64 + (lane & 15);
    const int row0 = rowBase + wr * 64 + ((lane >> 4) << 2);
    #pragma unroll
    for (int m = 0; m < 4; ++m) {
        #pragma unroll
        for (int q = 0; q < 4; ++q) {
            const int grow = row0 + m * 16 + q;
            const float xn = x2[grow];
            float* orow = out + (size_t)grow * NT;
            #pragma unroll
            for (int n = 0; n < 4; ++n) {
                const int gcol = col0 + n * 16;
                float sq = fmaxf(xn + y2[gcol] - 2.0f * acc[m][n][q], 0.0f);
                orow[gcol] = fminf(rsqrtf(sq), 1.0e6f);  // rsqrt(0)=inf -> clipped
            }
        }
    }
}

extern "C" void kernel_launch(void* const* d_in, const int* in_sizes, int n_in,
                              void* d_out, int out_size, void* d_ws, size_t ws_size,
                              hipStream_t stream)
{
    const float* x = (const float*)d_in[0];
    const float* y = (const float*)d_in[1];
    float* out = (float*)d_out;
    char* ws = (char*)d_ws;

    unsigned short* xb = (unsigned short*)ws;                 // 4 MB
    unsigned short* yb = (unsigned short*)(ws + (4u << 20));  // 8 MB
    float* x2 = (float*)(ws + (12u << 20));                   // 16 KB
    float* y2 = (float*)(ws + (12u << 20) + 4 * NB);          // 32 KB

    prep_kernel<<<(NB + NT) / 4, 256, 0, stream>>>(x, y, xb, yb, x2, y2, out);
    gemm_sim_kernel<<<2048, 256, 0, stream>>>(xb, yb, x2, y2, out + (size_t)NB * D);
}

// Round 20
// 57.521 us; speedup vs baseline: 2.2770x; 2.2770x over previous
//
#include <hip/hip_runtime.h>
#include <hip/hip_bf16.h>
#include <stdint.h>

typedef short bf16x8 __attribute__((ext_vector_type(8)));
typedef float f32x4 __attribute__((ext_vector_type(4)));

#define D  512
#define NB 4096
#define NT 8192

__device__ __forceinline__ unsigned short f2bf(float f) {
    __hip_bfloat16 h = __float2bfloat16(f);
    return *reinterpret_cast<unsigned short*>(&h);
}

// Fused fp32->bf16 convert + row squared-norm for BOTH inputs; x rows also
// write the fp32 passthrough (output 0). One wave per row. HBM-floor bound.
__global__ __launch_bounds__(256) void prep_kernel(
    const float* __restrict__ x, const float* __restrict__ y,
    unsigned short* __restrict__ xb, unsigned short* __restrict__ yb,
    float* __restrict__ x2, float* __restrict__ y2, float* __restrict__ copy)
{
    const int grow = blockIdx.x * 4 + (threadIdx.x >> 6);
    const int lane = threadIdx.x & 63;
    const bool isX = grow < NB;
    const int row  = isX ? grow : grow - NB;
    const float* src = isX ? x : y;
    unsigned short* dst = isX ? xb : yb;
    float* norms = isX ? x2 : y2;

    const float4* rp = reinterpret_cast<const float4*>(src + (size_t)row * D);
    float4 v0 = rp[lane * 2];
    float4 v1 = rp[lane * 2 + 1];
    if (isX) {
        float4* cp = reinterpret_cast<float4*>(copy + (size_t)row * D);
        cp[lane * 2]     = v0;
        cp[lane * 2 + 1] = v1;
    }
    float s = v0.x*v0.x + v0.y*v0.y + v0.z*v0.z + v0.w*v0.w
            + v1.x*v1.x + v1.y*v1.y + v1.z*v1.z + v1.w*v1.w;
    union { unsigned short h[8]; int4 v; } u;
    u.h[0] = f2bf(v0.x); u.h[1] = f2bf(v0.y); u.h[2] = f2bf(v0.z); u.h[3] = f2bf(v0.w);
    u.h[4] = f2bf(v1.x); u.h[5] = f2bf(v1.y); u.h[6] = f2bf(v1.z); u.h[7] = f2bf(v1.w);
    reinterpret_cast<int4*>(dst + (size_t)row * D)[lane] = u.v;
    #pragma unroll
    for (int off = 32; off > 0; off >>= 1) s += __shfl_xor(s, off);
    if (lane == 0) norms[row] = s;
}

// Best configuration (R17, 57.95 µs): m97-faithful 128x128 tile, BK=64,
// 4 waves (2x2, wave-tile 64x64), single 32 KiB LDS buffer, drain-per-
// K-step schedule, __launch_bounds__(256,4) -> 4 blocks/CU (16 waves/CU).
// Block-level TLP hides the drain stall and staggers store bursts across
// 4 co-resident generations (m114 mechanism) — the only lever that gained
// all session. XOR swizzle: source chunk g=(t&7)^((t>>3)&7), read-side
// per-lane constant; conflict-free b128 reads.
__global__ __launch_bounds__(256, 4) void gemm_sim_kernel(
    const unsigned short* __restrict__ X, const unsigned short* __restrict__ Y,
    const float* __restrict__ x2, const float* __restrict__ y2,
    float* __restrict__ out)
{
    __shared__ alignas(16) unsigned short lds[16384];   // 32 KiB

    const int t    = threadIdx.x;
    const int lane = t & 63;
    const int w    = t >> 6;          // 0..3
    const int wr   = w >> 1;          // 0..1 (row half, 64 rows)
    const int wc   = w & 1;           // 0..1 (col half, 64 cols)

    // 2048 blocks; per XCD 16 rowTiles x 16 colTiles (A 2MB + B 2MB L2-fit).
    const int bid = blockIdx.x;
    const int xcd = bid & 7;
    const int idx = bid >> 3;                          // 0..255
    const int rowBase = ((xcd & 1) * 16 + (idx & 15)) * 128;
    const int colBase = ((xcd >> 1) * 16 + (idx >> 4)) * 128;

    // Staging: thread t writes 16 B (8 ushorts) at LDS off t*8 (+L*2048),
    // i.e. row (t>>3)+L*32, stored chunk t&7. Source pre-swizzle (rule #21):
    // global chunk g = (t&7) ^ ((t>>3)&7)  (row&7 invariant under +32).
    const int g = ((t & 7) ^ ((t >> 3) & 7)) * 8;
    const unsigned short* gA = X + (size_t)(rowBase + (t >> 3)) * D + g;
    const unsigned short* gB = Y + (size_t)(colBase + (t >> 3)) * D + g;

    // Read-side swizzled chunk (per kk half): sc = (kk*4 + (lane>>4)) ^ (lane&7).
    int sc[2];
    #pragma unroll
    for (int kk = 0; kk < 2; ++kk)
        sc[kk] = (((kk << 2) | (lane >> 4)) ^ (lane & 7)) * 8;
    const int arow = (wr * 64 + (lane & 15)) * 64;          // + m*16*64 + sc
    const int brow = 8192 + (wc * 64 + (lane & 15)) * 64;   // + n*16*64 + sc

    f32x4 acc[4][4] = {};

#define STAGE(KT) do { \
    _Pragma("unroll") \
    for (int L = 0; L < 4; ++L) { \
        __builtin_amdgcn_global_load_lds( \
            (const __attribute__((address_space(1))) void*)(gA + (size_t)L * 32 * D + (KT) * 64), \
            (__attribute__((address_space(3))) void*)(lds + t * 8 + L * 2048), 16, 0, 0); \
        __builtin_amdgcn_global_load_lds( \
            (const __attribute__((address_space(1))) void*)(gB + (size_t)L * 32 * D + (KT) * 64), \
            (__attribute__((address_space(3))) void*)(lds + 8192 + t * 8 + L * 2048), 16, 0, 0); \
    } \
} while (0)

    // 8 K-steps (K=512 / BK=64), single-buffer drain schedule.
#pragma unroll
    for (int kt = 0; kt < 8; ++kt) {
        STAGE(kt);
        asm volatile("s_waitcnt vmcnt(0)" ::: "memory");
        __builtin_amdgcn_s_barrier();
        #pragma unroll
        for (int kk = 0; kk < 2; ++kk) {
            bf16x8 a[4], b[4];
            #pragma unroll
            for (int m = 0; m < 4; ++m)
                a[m] = *(const bf16x8*)(lds + arow + m * 1024 + sc[kk]);
            #pragma unroll
            for (int n = 0; n < 4; ++n)
                b[n] = *(const bf16x8*)(lds + brow + n * 1024 + sc[kk]);
            __builtin_amdgcn_s_setprio(1);
            #pragma unroll
            for (int m = 0; m < 4; ++m)
                #pragma unroll
                for (int n = 0; n < 4; ++n)
                    acc[m][n] = __builtin_amdgcn_mfma_f32_16x16x32_bf16(
                        a[m], b[n], acc[m][n], 0, 0, 0);
            __builtin_amdgcn_s_setprio(0);
        }
        asm volatile("s_waitcnt lgkmcnt(0)" ::: "memory");
        if (kt < 7) __builtin_amdgcn_s_barrier();
    }
#undef STAGE

    // Epilogue: C/D layout col = lane&15, row = (lane>>4)*4 + reg.
    const int col0 = colBase + wc * 64 + (lane & 15);
    const int row0 = rowBase + wr * 64 + ((lane >> 4) << 2);
    #pragma unroll
    for (int m = 0; m < 4; ++m) {
        #pragma unroll
        for (int q = 0; q < 4; ++q) {
            const int grow = row0 + m * 16 + q;
            const float xn = x2[grow];
            float* orow = out + (size_t)grow * NT;
            #pragma unroll
            for (int n = 0; n < 4; ++n) {
                const int gcol = col0 + n * 16;
                float sq = fmaxf(xn + y2[gcol] - 2.0f * acc[m][n][q], 0.0f);
                orow[gcol] = fminf(rsqrtf(sq), 1.0e6f);  // rsqrt(0)=inf -> clipped
            }
        }
    }
}

extern "C" void kernel_launch(void* const* d_in, const int* in_sizes, int n_in,
                              void* d_out, int out_size, void* d_ws, size_t ws_size,
                              hipStream_t stream)
{
    const float* x = (const float*)d_in[0];
    const float* y = (const float*)d_in[1];
    float* out = (float*)d_out;
    char* ws = (char*)d_ws;

    unsigned short* xb = (unsigned short*)ws;                 // 4 MB
    unsigned short* yb = (unsigned short*)(ws + (4u << 20));  // 8 MB
    float* x2 = (float*)(ws + (12u << 20));                   // 16 KB
    float* y2 = (float*)(ws + (12u << 20) + 4 * NB);          // 32 KB

    prep_kernel<<<(NB + NT) / 4, 256, 0, stream>>>(x, y, xb, yb, x2, y2, out);
    gemm_sim_kernel<<<2048, 256, 0, stream>>>(xb, yb, x2, y2, out + (size_t)NB * D);
}